// Round 6
// baseline (3309.327 us; speedup 1.0000x reference)
//
#include <hip/hip_runtime.h>

// 2-layer LSTM, B=512, T=1024, H=64 (tf LSTMCell, gates i,j,f,o, forget bias 1.0)
//
// ROUND-6 RESTRUCTURE: one wave (64 lanes) = one batch element, grid 512x64
// (2 waves/CU on separate SIMDs). Lane u owns hidden unit u: all 4 gate
// columns (i,j,f,o) for that unit = 260 W1 weights + 4 biases in VGPRs.
// Per step, IN-WAVE ONLY:
//   - h1 lives in registers (hv = h1[lane]); broadcast via 64 v_readlane
//   - 4 gate dots: 64 FMA each (SGPR h x VGPR w), 4-way split accumulators
//     (same summation order as rounds 3-5)
//   - lane-local activations + cell update (lane u has all 4 gates of unit u)
//   - layer 2 same-step: 4 DPP wave-sums + lane-63 scalar LSTM -> y[t]
// ZERO LDS exchange, ZERO barriers, ZERO replicated work. xs staged in LDS
// once (read amortized b128/4 steps); y buffered, stored float4/4 steps.
//
// Weight-residency (the rounds 3-5 failure): the backend remats loop-invariant
// weight loads into the loop whenever natural VGPR use exceeds its occupancy
// target, and launch_bounds' 2nd arg only sets a FLOOR on waves/EU. Fixes:
//   1) __attribute__((amdgpu_waves_per_eu(1,1))): occupancy target 1 wave/EU
//      -> allocator budget 512 VGPRs, no pressure-driven remat.
//   2) one-shot OPAQUE asm pass-through in the PROLOGUE: loop-used weights
//      are asm results, which LLVM cannot rematerialize or duplicate
//      (in-loop "+v" pins failed because the feeding load was re-executed).
// Success signature: VGPR_Count ~300. Failure signature: VGPR_Count < 100.

#define TT 1024

__device__ __forceinline__ float fsig(float x) {
    return __builtin_amdgcn_rcpf(1.f + __expf(-x));
}
__device__ __forceinline__ float ftanh(float x) {
    return 1.f - 2.f * __builtin_amdgcn_rcpf(1.f + __expf(2.f * x));
}

template <int Ctrl, int Rmask>
__device__ __forceinline__ float dpp_add(float x) {
    int t = __builtin_amdgcn_update_dpp(0, __float_as_int(x), Ctrl, Rmask, 0xf, true);
    return x + __int_as_float(t);
}
// Sum across 64 lanes; result valid in lane 63. 6 dependent VALU pairs.
__device__ __forceinline__ float wave_sum64(float x) {
    x = dpp_add<0x111, 0xf>(x); // row_shr:1
    x = dpp_add<0x112, 0xf>(x); // row_shr:2
    x = dpp_add<0x114, 0xf>(x); // row_shr:4
    x = dpp_add<0x118, 0xf>(x); // row_shr:8
    x = dpp_add<0x142, 0xa>(x); // row_bcast:15
    x = dpp_add<0x143, 0xc>(x); // row_bcast:31 ; lane63 = total
    return x;
}

// Broadcast lane `l` of v to all lanes via SGPR (no LDS, exec-independent).
__device__ __forceinline__ float bcast(float v, int l) {
    return __uint_as_float(__builtin_amdgcn_readlane(__float_as_uint(v), l));
}

__global__ __attribute__((amdgpu_waves_per_eu(1, 1))) __launch_bounds__(64)
void lstm2_kernel(
    const float* __restrict__ x,    // [B, T]
    const float* __restrict__ W1,   // [65, 256]; row0 = x, rows 1..64 = h1
    const float* __restrict__ b1,   // [256]
    const float* __restrict__ W2,   // [65, 4]; rows 0..63 = h1, row 64 = h2
    const float* __restrict__ b2,   // [4]
    float* __restrict__ y)          // [B, T]
{
    __shared__ __align__(16) float xs[TT];
    const int lane = threadIdx.x;   // 0..63 (one wave per block)
    const int b    = blockIdx.x;

    // stage x row into LDS (64 lanes x 4 float4 = 4 KB); same-wave RAW is
    // covered by compiler-inserted lgkmcnt (no barrier needed, 1 wave).
    {
        const float4* src = (const float4*)(x + (size_t)b * TT);
        float4* dst = (float4*)xs;
#pragma unroll
        for (int i = 0; i < 4; ++i) dst[(i << 6) | lane] = src[(i << 6) | lane];
    }

    // ---- weights: lane u owns unit u; gate g's column is g*64+u ----
    float wx[4], bs[4], wh[4][64];
#pragma unroll
    for (int g = 0; g < 4; ++g) {
        const int col = (g << 6) | lane;
        wx[g] = W1[col];                    // x-row weight
        bs[g] = b1[col];
#pragma unroll
        for (int j = 0; j < 64; ++j) wh[g][j] = W1[(j + 1) * 256 + col];
    }

    // One-shot opacity: after this, every loop-used weight is an asm RESULT
    // (not a load result) -> cannot be rematerialized into the loop.
#define PIN4(A, B, C, D) asm volatile("" : "+v"(A), "+v"(B), "+v"(C), "+v"(D))
#pragma unroll
    for (int g = 0; g < 4; ++g) {
#pragma unroll
        for (int j = 0; j < 64; j += 4)
            PIN4(wh[g][j], wh[g][j + 1], wh[g][j + 2], wh[g][j + 3]);
    }
    PIN4(wx[0], wx[1], wx[2], wx[3]);
    PIN4(bs[0], bs[1], bs[2], bs[3]);
#undef PIN4

    // layer-2 constants
    const float4 w2g4 = *(const float4*)(W2 + lane * 4);   // W2[lane][0..3]
    const float w2h0 = W2[256], w2h1 = W2[257], w2h2 = W2[258], w2h3 = W2[259];
    const float b20 = b2[0], b21 = b2[1], b22 = b2[2], b23 = b2[3];

    float c1 = 0.f, hv = 0.f;     // layer-1 state of unit `lane`
    float c2 = 0.f, h2 = 0.f;     // layer-2 state (meaningful in lane 63 only;
                                  // other lanes compute garbage, never read)
    float* yrow = y + (size_t)b * TT;

    // One step. Broadcasts hoisted so CSE across the 4 gates is explicit.
    // Summation order (4-way split per gate) matches rounds 3-5 numerics.
#define STEP(XT, YB) { \
        float hbc[64]; \
        _Pragma("unroll") \
        for (int j = 0; j < 64; ++j) hbc[j] = bcast(hv, j); \
        float p[4]; \
        _Pragma("unroll") \
        for (int g = 0; g < 4; ++g) { \
            float a0 = fmaf((XT), wx[g], bs[g]), a1 = 0.f, a2 = 0.f, a3 = 0.f; \
            _Pragma("unroll") \
            for (int j = 0; j < 64; j += 4) { \
                a0 = fmaf(hbc[j + 0], wh[g][j + 0], a0); \
                a1 = fmaf(hbc[j + 1], wh[g][j + 1], a1); \
                a2 = fmaf(hbc[j + 2], wh[g][j + 2], a2); \
                a3 = fmaf(hbc[j + 3], wh[g][j + 3], a3); \
            } \
            p[g] = (a0 + a1) + (a2 + a3); \
        } \
        const float i_ = fsig(p[0]); \
        const float j_ = ftanh(p[1]); \
        const float f_ = fsig(p[2] + 1.f); \
        const float o_ = fsig(p[3]); \
        c1 = fmaf(c1, f_, i_ * j_); \
        hv = ftanh(c1) * o_; \
        const float d0 = wave_sum64(hv * w2g4.x); \
        const float d1 = wave_sum64(hv * w2g4.y); \
        const float d2 = wave_sum64(hv * w2g4.z); \
        const float d3 = wave_sum64(hv * w2g4.w); \
        const float i2 = fsig (fmaf(h2, w2h0, d0) + b20); \
        const float j2 = ftanh(fmaf(h2, w2h1, d1) + b21); \
        const float f2 = fsig (fmaf(h2, w2h2, d2) + b22 + 1.f); \
        const float o2 = fsig (fmaf(h2, w2h3, d3) + b23); \
        c2 = fmaf(c2, f2, i2 * j2); \
        h2 = ftanh(c2) * o2; \
        YB = h2; }

    for (int t = 0; t < TT; t += 4) {
        float4 x4 = *(const float4*)(xs + t);
        float4 yb;
        STEP(x4.x, yb.x)
        STEP(x4.y, yb.y)
        STEP(x4.z, yb.z)
        STEP(x4.w, yb.w)
        if (lane == 63) *(float4*)(yrow + t) = yb;   // y[t-3..t] from lane 63
    }
#undef STEP
}

extern "C" void kernel_launch(void* const* d_in, const int* in_sizes, int n_in,
                              void* d_out, int out_size, void* d_ws, size_t ws_size,
                              hipStream_t stream) {
    const float* x  = (const float*)d_in[0];
    const float* W1 = (const float*)d_in[1];
    const float* b1 = (const float*)d_in[2];
    const float* W2 = (const float*)d_in[3];
    const float* b2 = (const float*)d_in[4];
    float* y = (float*)d_out;
    lstm2_kernel<<<512, 64, 0, stream>>>(x, W1, b1, W2, b2, y);
}

// Round 7
// 749.168 us; speedup vs baseline: 4.4173x; 4.4173x over previous
//
#include <hip/hip_runtime.h>

// 2-layer LSTM, B=512, T=1024, H=64 (tf LSTMCell, gates i,j,f,o, forget bias 1.0)
//
// ROUND-7: TWO waves per batch element, TWO gates per wave.
// Grid 512 x 128 thr (2 waves/block, 2 blocks/CU -> 1 wave/SIMD, 4 SIMDs busy).
// Wave w owns gates {2w, 2w+1}: 2x65 W1 weights + biases = ~134 VGPRs + temps
// ~= 180 < 256 arch-VGPR ceiling (round 6 proved waves_per_eu(1,1) + one-shot
// opaque pins defeat remat, but 4 gates/wave = 264 regs overflowed -> 3.7 GB
// of scratch traffic). Each 64-readlane broadcast of hv feeds 128 FMAs (2x
// the amortization of the round-3 4-wave split).
// Per step (ONE barrier):
//   pre-barrier : j-outer matvec for both gates (shared broadcasts);
//                 layer-2 dots via DPP wave_sum64 on PRE-update hv (=h1[t-1]);
//                 acts -> gls[par][gate][unit] (2/bank, conflict-free);
//                 lane63 -> dls[par][gate].
//   post-barrier: read 4 acts (conflict-free b32), cell update -> new hv
//                 (replicated per wave, register-resident);
//                 wave 0 only: scalar layer-2 recurrence for step t-1 using
//                 dls[par] (uniform b128), store y[t-1] from tid 0.
// Epilogue computes y[TT-1]. Parity double-buffering keeps all LDS addresses
// static; t-loop unrolled x4.

#define TT 1024

__device__ __forceinline__ float fsig(float x) {
    return __builtin_amdgcn_rcpf(1.f + __expf(-x));
}
__device__ __forceinline__ float ftanh(float x) {
    return 1.f - 2.f * __builtin_amdgcn_rcpf(1.f + __expf(2.f * x));
}

template <int Ctrl, int Rmask>
__device__ __forceinline__ float dpp_add(float x) {
    int t = __builtin_amdgcn_update_dpp(0, __float_as_int(x), Ctrl, Rmask, 0xf, true);
    return x + __int_as_float(t);
}
// Sum across 64 lanes; result valid in lane 63. 6 dependent VALU pairs.
__device__ __forceinline__ float wave_sum64(float x) {
    x = dpp_add<0x111, 0xf>(x); // row_shr:1
    x = dpp_add<0x112, 0xf>(x); // row_shr:2
    x = dpp_add<0x114, 0xf>(x); // row_shr:4
    x = dpp_add<0x118, 0xf>(x); // row_shr:8
    x = dpp_add<0x142, 0xa>(x); // row_bcast:15
    x = dpp_add<0x143, 0xc>(x); // row_bcast:31 ; lane63 = total
    return x;
}

// Broadcast lane `l` of v to all lanes via SGPR (no LDS, exec-independent).
__device__ __forceinline__ float bcast(float v, int l) {
    return __uint_as_float(__builtin_amdgcn_readlane(__float_as_uint(v), l));
}

__global__ __attribute__((amdgpu_waves_per_eu(1, 1))) __launch_bounds__(128)
void lstm2_kernel(
    const float* __restrict__ x,    // [B, T]
    const float* __restrict__ W1,   // [65, 256]; row0 = x, rows 1..64 = h1
    const float* __restrict__ b1,   // [256]
    const float* __restrict__ W2,   // [65, 4]; rows 0..63 = h1, row 64 = h2
    const float* __restrict__ b2,   // [4]
    float* __restrict__ y)          // [B, T]
{
    __shared__ __align__(16) float xs[TT];
    __shared__ __align__(16) float gls[2][4][64];  // [parity][gate][unit] acts
    __shared__ __align__(16) float dls[2][4];      // [parity][gate] layer-2 dots

    const int tid  = threadIdx.x;
    const int lane = tid & 63;
    const int wid  = tid >> 6;       // 0 or 1
    const int b    = blockIdx.x;

    // stage x row (128 thr x 2 float4 = 4 KB, coalesced)
    {
        const float4* src = (const float4*)(x + (size_t)b * TT);
        float4* dst = (float4*)xs;
        dst[tid]       = src[tid];
        dst[128 + tid] = src[128 + tid];
    }

    const int ga = wid << 1, gb = ga | 1;       // this wave's two gates
    const int ca = (ga << 6) | lane;            // gate columns for unit `lane`
    const int cb = (gb << 6) | lane;

    // weights: 2 full columns in VGPRs
    float wxa = W1[ca], wxb = W1[cb];
    float bsa = b1[ca], bsb = b1[cb];
    float wha[64], whb[64];
#pragma unroll
    for (int j = 0; j < 64; ++j) {
        wha[j] = W1[(j + 1) * 256 + ca];
        whb[j] = W1[(j + 1) * 256 + cb];
    }
    // one-shot opacity: loop-used weights become asm results -> non-rematable
#define PIN4(A, B, C, D) asm volatile("" : "+v"(A), "+v"(B), "+v"(C), "+v"(D))
#pragma unroll
    for (int j = 0; j < 64; j += 4) {
        PIN4(wha[j], wha[j + 1], wha[j + 2], wha[j + 3]);
        PIN4(whb[j], whb[j + 1], whb[j + 2], whb[j + 3]);
    }
    PIN4(wxa, wxb, bsa, bsb);
#undef PIN4

    // layer-2 weights
    const float w2ga = W2[lane * 4 + ga];
    const float w2gb = W2[lane * 4 + gb];
    const float w2h0 = W2[256], w2h1 = W2[257], w2h2 = W2[258], w2h3 = W2[259];
    const float b20 = b2[0], b21 = b2[1], b22 = b2[2], b23 = b2[3];

    // unified activation constants (wave-uniform):
    //   ga in {0,2}: sigmoid (f adds forget bias via kk)
    //   gb in {1,3}: tanh for gate 1, sigmoid for gate 3
    const float L2E = 1.4426950408889634f;
    const float mma = -L2E;
    const float kka = (ga == 2) ? -L2E : 0.f;
    const float mmb = (gb == 1) ? 2.f * L2E : -L2E;
    const float aab = (gb == 1) ? 1.f : 0.f;
    const float bbb = (gb == 1) ? -2.f : 1.f;

    float c1 = 0.f, hv = 0.f;     // layer-1 state of unit `lane` (per-wave copy)
    float c2v = 0.f, h2v = 0.f;   // layer-2 state (wave 0, uniform lanes)
    float* yrow = y + (size_t)b * TT;

    __syncthreads();              // xs staged

    // One step. PAR compile-time; DOL2 wave-uniform; YI = t-1.
    // Matvec: j-outer so each broadcast quad feeds both gates (8 FMA / 4 rl).
    // Summation: 4-way split accumulators, (a0+a1)+(a2+a3) (rounds 3-6 order).
#define STEP(PAR, XT, DOL2, YI) { \
        float a0 = fmaf((XT), wxa, bsa), a1 = 0.f, a2 = 0.f, a3 = 0.f; \
        float e0 = fmaf((XT), wxb, bsb), e1 = 0.f, e2 = 0.f, e3 = 0.f; \
        _Pragma("unroll") \
        for (int j = 0; j < 64; j += 4) { \
            const float s0 = bcast(hv, j + 0), s1 = bcast(hv, j + 1); \
            const float s2 = bcast(hv, j + 2), s3 = bcast(hv, j + 3); \
            a0 = fmaf(s0, wha[j + 0], a0); e0 = fmaf(s0, whb[j + 0], e0); \
            a1 = fmaf(s1, wha[j + 1], a1); e1 = fmaf(s1, whb[j + 1], e1); \
            a2 = fmaf(s2, wha[j + 2], a2); e2 = fmaf(s2, whb[j + 2], e2); \
            a3 = fmaf(s3, wha[j + 3], a3); e3 = fmaf(s3, whb[j + 3], e3); \
        } \
        const float pa = (a0 + a1) + (a2 + a3); \
        const float pb = (e0 + e1) + (e2 + e3); \
        const float da = wave_sum64(hv * w2ga);   /* dots of h1[t-1] */ \
        const float db = wave_sum64(hv * w2gb); \
        const float acta = __builtin_amdgcn_rcpf(1.f + exp2f(fmaf(mma, pa, kka))); \
        const float actb = fmaf(bbb, __builtin_amdgcn_rcpf(1.f + exp2f(mmb * pb)), aab); \
        gls[PAR][ga][lane] = acta; \
        gls[PAR][gb][lane] = actb; \
        if (lane == 63) { dls[PAR][ga] = da; dls[PAR][gb] = db; } \
        __syncthreads();          /* the ONLY barrier per step */ \
        { \
            const float i_ = gls[PAR][0][lane], j_ = gls[PAR][1][lane]; \
            const float f_ = gls[PAR][2][lane], o_ = gls[PAR][3][lane]; \
            c1 = fmaf(c1, f_, i_ * j_); \
            hv = ftanh(c1) * o_; \
        } \
        if (wid == 0 && (DOL2)) {  /* scalar layer-2 for step t-1, wave 0 */ \
            const float4 d4 = *(const float4*)(&dls[PAR][0]); \
            const float i2 = fsig (fmaf(h2v, w2h0, d4.x) + b20); \
            const float j2 = ftanh(fmaf(h2v, w2h1, d4.y) + b21); \
            const float f2 = fsig (fmaf(h2v, w2h2, d4.z) + b22 + 1.f); \
            const float o2 = fsig (fmaf(h2v, w2h3, d4.w) + b23); \
            c2v = fmaf(c2v, f2, i2 * j2); \
            h2v = ftanh(c2v) * o2; \
            if (lane == 0) yrow[YI] = h2v; \
        } }

    for (int t = 0; t < TT; t += 4) {
        const float4 x4 = *(const float4*)(xs + t);
        STEP(0, x4.x, t > 0, t - 1)     // dls holds d(h1[-1])=0 at t=0: skip
        STEP(1, x4.y, true,  t + 0)
        STEP(0, x4.z, true,  t + 1)
        STEP(1, x4.w, true,  t + 2)
    }
#undef STEP

    // epilogue: y[TT-1] needs dots of h1[TT-1] (the final hv)
    {
        const float da = wave_sum64(hv * w2ga);
        const float db = wave_sum64(hv * w2gb);
        if (lane == 63) { dls[0][ga] = da; dls[0][gb] = db; }
        __syncthreads();
        if (tid == 0) {
            const float4 d4 = *(const float4*)(&dls[0][0]);
            const float i2 = fsig (fmaf(h2v, w2h0, d4.x) + b20);
            const float j2 = ftanh(fmaf(h2v, w2h1, d4.y) + b21);
            const float f2 = fsig (fmaf(h2v, w2h2, d4.z) + b22 + 1.f);
            const float o2 = fsig (fmaf(h2v, w2h3, d4.w) + b23);
            c2v = fmaf(c2v, f2, i2 * j2);
            h2v = ftanh(c2v) * o2;
            yrow[TT - 1] = h2v;
        }
    }
}

extern "C" void kernel_launch(void* const* d_in, const int* in_sizes, int n_in,
                              void* d_out, int out_size, void* d_ws, size_t ws_size,
                              hipStream_t stream) {
    const float* x  = (const float*)d_in[0];
    const float* W1 = (const float*)d_in[1];
    const float* b1 = (const float*)d_in[2];
    const float* W2 = (const float*)d_in[3];
    const float* b2 = (const float*)d_in[4];
    float* y = (float*)d_out;
    lstm2_kernel<<<512, 128, 0, stream>>>(x, W1, b1, W2, b2, y);
}